// Round 23
// baseline (76.266 us; speedup 1.0000x reference)
//
#include <hip/hip_runtime.h>

static constexpr float DEG2RAD = 0.017453292519943295f;
static constexpr float MSG_SCALE   = 0.015625f;  // 1/64: f16 overflow headroom
static constexpr float MSG_UNSCALE = 64.0f;
// Primary: f16x2 packed-atomic scan
static constexpr int B_NH   = 40000;  // nodes/bucket; f16x2 hist = 156.25KB LDS
static constexpr int NBH    = 3;
static constexpr int MAX_NSH= 80;     // grid = 3*80 = 240 <= 256
// Mid fallback (R19, proven 75.9us) params
static constexpr int B_N1   = 20000;
static constexpr int NB1    = 5;
static constexpr int MAX_NS1= 48;

typedef __fp16 f16x2 __attribute__((ext_vector_type(2)));

__device__ __forceinline__ unsigned lds_off(const void* p) {
    return (unsigned)(unsigned long long)p;
}

// One packed f16x2 LDS atomic add: accumulates (P,Q) in a single lane-op.
__device__ __forceinline__ void ds_pk_add(unsigned addr, float p, float q) {
    f16x2 v = __builtin_amdgcn_cvt_pkrtz(p, q);   // v_cvt_pkrtz_f16_f32
    asm volatile("ds_pk_add_f16 %0, %1" :: "v"(addr),
                 "v"(__builtin_bit_cast(unsigned, v)) : "memory");
}

// Also zeroes d_out (saves a memset dispatch; stream-ordered before reduce).
__global__ void __launch_bounds__(256) node_ef_kernel(
    const float* __restrict__ x, const float* __restrict__ xymean,
    const float* __restrict__ xystd, float2* __restrict__ ef,
    float* __restrict__ out, int n)
{
    int i = blockIdx.x * 256 + threadIdx.x;
    if (i == 0) *out = 0.0f;
    if (i >= n) return;
    float vm = fmaf(x[i * 6 + 0], xystd[0], xymean[0]);
    float va = fmaf(x[i * 6 + 1], xystd[1], xymean[1]) * DEG2RAD;
    float s, c;
    sincosf(va, &s, &c);
    ef[i] = make_float2(vm * c, vm * s);
}

// f16x2-histogram scan, 8 edges/thread/round (halves round count: the
// measured residual is a fixed per-round cost, not atomics/gathers).
__global__ void __launch_bounds__(1024) scan_h_kernel(
    const int* __restrict__ src, const int* __restrict__ dst,
    const float2* __restrict__ eattr, const float2* __restrict__ ef,
    const float* __restrict__ edgemean, const float* __restrict__ edgestd,
    unsigned* __restrict__ partial, int ne, int slice)
{
    __shared__ unsigned sAgg[B_NH];   // 156.25 KB (f16x2 per node)
    const int xp = blockIdx.x & 7, t = blockIdx.x >> 3;
    const int b  = t % NBH;
    const int sp = (t / NBH) * 8 + xp;   // same-slice blocks share an XCD/L2
    const int base = b * B_NH;
    for (int l = threadIdx.x; l < B_NH; l += 1024) sAgg[l] = 0u;
    __syncthreads();
    const int e0 = sp * slice;
    const int e1 = min(ne, e0 + slice);
    const float em0 = edgemean[0], em1 = edgemean[1];
    const float es0 = edgestd[0],  es1 = edgestd[1];

    auto process = [&](int si, int di, int e) {
        unsigned ls = (unsigned)(si - base);
        unsigned ld = (unsigned)(di - base);
        bool hs = ls < (unsigned)B_NH;
        bool hd = ld < (unsigned)B_NH;
        if (!(hs || hd)) return;
        float2 ea = eattr[e];
        float r  = fmaf(ea.x, es0, em0);
        float xr = fmaf(ea.y, es1, em1);
        float inv = MSG_SCALE / fmaf(r, r, xr * xr);
        float g  = r * inv;            // pre-scaled by 1/64
        float bb = -xr * inv;
        float2 efi = ef[si];
        float2 efj = ef[di];
        float ei_ = efi.x, fi = efi.y, ej_ = efj.x, fj = efj.y;
        // A = e_i*e_j - e_i^2 + f_i*f_j - f_i^2 ; B = f_i*e_j - e_i*f_j
        float A1 = fmaf(ei_, ej_ - ei_, fi * (fj - fi));
        float B1 = fmaf(fi, ej_, -ei_ * fj);
        if (hs) {
            ds_pk_add(lds_off(&sAgg[ls]),
                      fmaf(g, A1, bb * B1), fmaf(g, B1, -bb * A1));
        }
        if (hd) {
            float A2 = fmaf(ej_, ei_ - ej_, fj * (fi - fj));
            ds_pk_add(lds_off(&sAgg[ld]),
                      fmaf(g, A2, -bb * B1), fmaf(-g, B1, -bb * A2));
        }
    };

    // slice multiple of 8 -> 8-edge groups never straddle e1.
    for (int e = e0 + 8 * (int)threadIdx.x; e < e1; e += 8192) {
        int4 ssA = *(const int4*)(src + e);
        int4 ddA = *(const int4*)(dst + e);
        int4 ssB = *(const int4*)(src + e + 4);
        int4 ddB = *(const int4*)(dst + e + 4);
        process(ssA.x, ddA.x, e);
        process(ssA.y, ddA.y, e + 1);
        process(ssA.z, ddA.z, e + 2);
        process(ssA.w, ddA.w, e + 3);
        process(ssB.x, ddB.x, e + 4);
        process(ssB.y, ddB.y, e + 5);
        process(ssB.z, ddB.z, e + 6);
        process(ssB.w, ddB.w, e + 7);
    }
    __syncthreads();
    unsigned* outp = partial + ((size_t)sp * NBH + b) * B_NH;
    for (int l = threadIdx.x; l < B_NH; l += 1024) outp[l] = sAgg[l];
}

// Reduce: 4 nodes/thread via uint4 bin loads (ns independent dwordx4 per
// lane = max MLP), f32 accum, unscale, fused MSE.
__global__ void __launch_bounds__(256) reduce_h_kernel(
    const float* __restrict__ x, const float* __restrict__ y,
    const float* __restrict__ xymean, const float* __restrict__ xystd,
    const unsigned* __restrict__ partial, float* __restrict__ out,
    int n, int ns)
{
    int i0 = (blockIdx.x * 256 + threadIdx.x) * 4;
    float v = 0.0f;
    const float inv_n = 1.0f / (float)n;
    if (i0 < n) {
        int b = i0 / B_NH;          // B_NH mult of 4 -> all 4 nodes same bucket
        int l = i0 - b * B_NH;
        const unsigned* p = partial + (size_t)b * B_NH + l;
        const size_t stride = (size_t)NBH * B_NH;
        float P[4] = {0, 0, 0, 0}, Q[4] = {0, 0, 0, 0};
        for (int s = 0; s < ns; ++s) {
            uint4 w = *(const uint4*)(p + (size_t)s * stride);
            f16x2 h0 = __builtin_bit_cast(f16x2, w.x);
            f16x2 h1 = __builtin_bit_cast(f16x2, w.y);
            f16x2 h2 = __builtin_bit_cast(f16x2, w.z);
            f16x2 h3 = __builtin_bit_cast(f16x2, w.w);
            P[0] += (float)h0.x; Q[0] += (float)h0.y;
            P[1] += (float)h1.x; Q[1] += (float)h1.y;
            P[2] += (float)h2.x; Q[2] += (float)h2.y;
            P[3] += (float)h3.x; Q[3] += (float)h3.y;
        }
        #pragma unroll
        for (int k = 0; k < 4; ++k) {
            int i = i0 + k;
            if (i >= n) break;
            float Pk = P[k] * MSG_UNSCALE;
            float Qk = Q[k] * MSG_UNSCALE;
            float xd2 = fmaf(x[i * 6 + 2], xystd[2], xymean[2]);
            float xd3 = fmaf(x[i * 6 + 3], xystd[3], xymean[3]);
            float dP = xd2 - Pk;
            float dQ = xd3 - Qk;
            float dpq = fmaf(dP, dP, dQ * dQ);
            float msep = 0.0f;
            #pragma unroll
            for (int c = 0; c < 6; ++c) {
                float dxy = x[i * 6 + c] - y[i * 6 + c];
                msep = fmaf(dxy, dxy, msep);
            }
            v += dpq * (0.01f * inv_n) + msep * (0.5f / 6.0f * inv_n);
        }
    }
    #pragma unroll
    for (int off = 32; off; off >>= 1) v += __shfl_down(v, off, 64);
    __shared__ float ls_[4];
    int lane = threadIdx.x & 63, wv = threadIdx.x >> 6;
    if (lane == 0) ls_[wv] = v;
    __syncthreads();
    if (threadIdx.x == 0) atomicAdd(out, ls_[0] + ls_[1] + ls_[2] + ls_[3]);
}

// ---- proven f32 fallback path (R19) ----
template <int BN, bool SW>
__global__ void __launch_bounds__(1024) scan_kernel(
    const int* __restrict__ src, const int* __restrict__ dst,
    const float2* __restrict__ eattr, const float2* __restrict__ ef,
    const float* __restrict__ edgemean, const float* __restrict__ edgestd,
    float2* __restrict__ partial, int ne, int nb, int slice)
{
    __shared__ float2 sAgg[BN];
    int b, sp;
    if (SW) {
        int xp = blockIdx.x & 7, t = blockIdx.x >> 3;
        b  = t % nb;
        sp = (t / nb) * 8 + xp;
    } else {
        b  = blockIdx.x % nb;
        sp = blockIdx.x / nb;
    }
    const int base = b * BN;
    for (int l = threadIdx.x; l < BN; l += 1024) sAgg[l] = make_float2(0.f, 0.f);
    __syncthreads();
    const int e0 = sp * slice;
    const int e1 = min(ne, e0 + slice);
    const float em0 = edgemean[0], em1 = edgemean[1];
    const float es0 = edgestd[0],  es1 = edgestd[1];
    auto process = [&](int si, int di, int e) {
        unsigned ls = (unsigned)(si - base);
        unsigned ld = (unsigned)(di - base);
        bool hs = ls < (unsigned)BN;
        bool hd = ld < (unsigned)BN;
        if (!(hs || hd)) return;
        float2 ea = eattr[e];
        float r  = fmaf(ea.x, es0, em0);
        float xr = fmaf(ea.y, es1, em1);
        float inv = 1.0f / fmaf(r, r, xr * xr);
        float g  = r * inv;
        float bb = -xr * inv;
        float2 efi = ef[si];
        float2 efj = ef[di];
        float ei_ = efi.x, fi = efi.y, ej_ = efj.x, fj = efj.y;
        float A1 = fmaf(ei_, ej_ - ei_, fi * (fj - fi));
        float B1 = fmaf(fi, ej_, -ei_ * fj);
        if (hs) {
            atomicAdd(&sAgg[ls].x, fmaf(g, A1, bb * B1));
            atomicAdd(&sAgg[ls].y, fmaf(g, B1, -bb * A1));
        }
        if (hd) {
            float A2 = fmaf(ej_, ei_ - ej_, fj * (fi - fj));
            atomicAdd(&sAgg[ld].x, fmaf(g, A2, -bb * B1));
            atomicAdd(&sAgg[ld].y, fmaf(-g, B1, -bb * A2));
        }
    };
    for (int e = e0 + 4 * (int)threadIdx.x; e < e1; e += 4096) {
        int4 ss = *(const int4*)(src + e);
        int4 dd = *(const int4*)(dst + e);
        process(ss.x, dd.x, e);
        process(ss.y, dd.y, e + 1);
        process(ss.z, dd.z, e + 2);
        process(ss.w, dd.w, e + 3);
    }
    __syncthreads();
    float2* outp = partial + ((size_t)sp * nb + b) * BN;
    for (int l = threadIdx.x; l < BN; l += 1024) outp[l] = sAgg[l];
}

__global__ void __launch_bounds__(256) edge_atomic_kernel(
    const int* __restrict__ eidx, const float2* __restrict__ eattr,
    const float2* __restrict__ ef, const float* __restrict__ edgemean,
    const float* __restrict__ edgestd, float* __restrict__ agg, int ne)
{
    int e = blockIdx.x * 256 + threadIdx.x;
    if (e >= ne) return;
    int s = eidx[e];
    int d = eidx[ne + e];
    float2 ea = eattr[e];
    float r  = fmaf(ea.x, edgestd[0], edgemean[0]);
    float xr = fmaf(ea.y, edgestd[1], edgemean[1]);
    float inv = 1.0f / fmaf(r, r, xr * xr);
    float g = r * inv;
    float b = -xr * inv;
    float2 efi = ef[s];
    float2 efj = ef[d];
    float ei_ = efi.x, fi = efi.y, ej_ = efj.x, fj = efj.y;
    float A1 = fmaf(ei_, ej_ - ei_, fi * (fj - fi));
    float B1 = fmaf(fi, ej_, -ei_ * fj);
    float A2 = fmaf(ej_, ei_ - ej_, fj * (fi - fj));
    atomicAdd(&agg[2 * s],     fmaf(g, A1, b * B1));
    atomicAdd(&agg[2 * s + 1], fmaf(g, B1, -b * A1));
    atomicAdd(&agg[2 * d],     fmaf(g, A2, -b * B1));
    atomicAdd(&agg[2 * d + 1], fmaf(-g, B1, -b * A2));
}

__global__ void __launch_bounds__(256) reduce_kernel(
    const float* __restrict__ x, const float* __restrict__ y,
    const float* __restrict__ xymean, const float* __restrict__ xystd,
    const float2* __restrict__ partial, float* __restrict__ out,
    int n, int nb, int bn, int ns)
{
    int i = blockIdx.x * 256 + threadIdx.x;
    float v = 0.0f;
    if (i < n) {
        float P = 0.0f, Q = 0.0f;
        if (ns > 0) {
            int b = i / bn;
            int l = i - b * bn;
            const float2* p = partial + (size_t)b * bn + l;
            const size_t stride = (size_t)nb * bn;
            for (int s = 0; s < ns; ++s) {
                float2 a = p[(size_t)s * stride];
                P += a.x;
                Q += a.y;
            }
        } else {
            float2 a = partial[i];
            P = a.x;
            Q = a.y;
        }
        float xd2 = fmaf(x[i * 6 + 2], xystd[2], xymean[2]);
        float xd3 = fmaf(x[i * 6 + 3], xystd[3], xymean[3]);
        float dP = xd2 - P;
        float dQ = xd3 - Q;
        float dpq = fmaf(dP, dP, dQ * dQ);
        float msep = 0.0f;
        #pragma unroll
        for (int c = 0; c < 6; ++c) {
            float dxy = x[i * 6 + c] - y[i * 6 + c];
            msep = fmaf(dxy, dxy, msep);
        }
        v = dpq * (0.01f / (float)n) + msep * (0.5f / (6.0f * (float)n));
    }
    #pragma unroll
    for (int off = 32; off; off >>= 1) v += __shfl_down(v, off, 64);
    __shared__ float ls_[4];
    int lane = threadIdx.x & 63, wv = threadIdx.x >> 6;
    if (lane == 0) ls_[wv] = v;
    __syncthreads();
    if (threadIdx.x == 0) atomicAdd(out, ls_[0] + ls_[1] + ls_[2] + ls_[3]);
}

extern "C" void kernel_launch(void* const* d_in, const int* in_sizes, int n_in,
                              void* d_out, int out_size, void* d_ws, size_t ws_size,
                              hipStream_t stream) {
    const float* x        = (const float*)d_in[0];
    const int*   eidx     = (const int*)d_in[1];
    const float* eattr    = (const float*)d_in[2];
    const float* y        = (const float*)d_in[3];
    const float* xymean   = (const float*)d_in[4];
    const float* xystd    = (const float*)d_in[5];
    const float* edgemean = (const float*)d_in[6];
    const float* edgestd  = (const float*)d_in[7];
    float* out = (float*)d_out;

    const int n  = in_sizes[0] / 6;   // 100000 nodes
    const int ne = in_sizes[2] / 2;   // 1600000 edges

    const size_t ef_bytes = (size_t)n * sizeof(float2);   // 0.8 MB

    // ---- primary: f16x2 packed-atomic scan (nb=3, ns up to 80) ----
    {
        const size_t per_split = (size_t)NBH * B_NH * sizeof(unsigned); // 480 KB
        int ns = 0;
        if (ws_size > ef_bytes) {
            size_t fit = (ws_size - ef_bytes) / per_split;
            ns = (fit > (size_t)MAX_NSH) ? MAX_NSH : (int)fit;
        }
        ns &= ~7;
        if (ns >= 8) {
            unsigned* partial = (unsigned*)d_ws;
            float2* ef = (float2*)((char*)d_ws + per_split * ns);
            node_ef_kernel<<<(n + 255) / 256, 256, 0, stream>>>(
                x, xymean, xystd, ef, out, n);
            int slice = ((ne + ns - 1) / ns + 7) & ~7;   // multiple of 8
            scan_h_kernel<<<NBH * ns, 1024, 0, stream>>>(
                eidx, eidx + ne, (const float2*)eattr, ef, edgemean, edgestd,
                partial, ne, slice);
            reduce_h_kernel<<<(n / 4 + 255) / 256, 256, 0, stream>>>(
                x, y, xymean, xystd, partial, out, n, ns);
            return;
        }
    }

    (void)hipMemsetAsync(out, 0, sizeof(float), stream);

    // ---- mid: R19 f32 5-bucket scan ----
    {
        const size_t per_split = (size_t)NB1 * B_N1 * sizeof(float2); // 0.8 MB
        int ns = 0;
        if (ws_size > ef_bytes) {
            size_t fit = (ws_size - ef_bytes) / per_split;
            ns = (fit > (size_t)MAX_NS1) ? MAX_NS1 : (int)fit;
        }
        if (ns >= 1) {
            bool sw = (ns >= 8);
            if (sw) ns &= ~7;
            float2* partial = (float2*)d_ws;
            float2* ef = (float2*)((char*)d_ws + per_split * ns);
            node_ef_kernel<<<(n + 255) / 256, 256, 0, stream>>>(
                x, xymean, xystd, ef, out, n);
            int slice = ((ne + ns - 1) / ns + 3) & ~3;
            if (sw) {
                scan_kernel<B_N1, true><<<NB1 * ns, 1024, 0, stream>>>(
                    eidx, eidx + ne, (const float2*)eattr, ef, edgemean, edgestd,
                    partial, ne, NB1, slice);
            } else {
                scan_kernel<B_N1, false><<<NB1 * ns, 1024, 0, stream>>>(
                    eidx, eidx + ne, (const float2*)eattr, ef, edgemean, edgestd,
                    partial, ne, NB1, slice);
            }
            reduce_kernel<<<(n + 255) / 256, 256, 0, stream>>>(
                x, y, xymean, xystd, partial, out, n, NB1, B_N1, ns);
            return;
        }
    }

    // ---- tiny-ws fallback: global atomics ----
    {
        float2* agg = (float2*)d_ws;
        float2* ef = (float2*)((char*)d_ws + (size_t)n * sizeof(float2));
        (void)hipMemsetAsync(agg, 0, (size_t)n * sizeof(float2), stream);
        node_ef_kernel<<<(n + 255) / 256, 256, 0, stream>>>(
            x, xymean, xystd, ef, out, n);
        edge_atomic_kernel<<<(ne + 255) / 256, 256, 0, stream>>>(
            eidx, (const float2*)eattr, ef, edgemean, edgestd, (float*)agg, ne);
        reduce_kernel<<<(n + 255) / 256, 256, 0, stream>>>(
            x, y, xymean, xystd, agg, out, n, 1, 1, 0);
    }
}

// Round 24
// 58.066 us; speedup vs baseline: 1.3134x; 1.3134x over previous
//
#include <hip/hip_runtime.h>

static constexpr float DEG2RAD = 0.017453292519943295f;
static constexpr float MSG_SCALE   = 0.015625f;  // 1/64: f16 overflow headroom
static constexpr float MSG_UNSCALE = 64.0f;
// Primary: f16x2 packed-atomic scan
static constexpr int B_NH   = 40000;  // nodes/bucket; f16x2 hist = 156.25KB LDS
static constexpr int NBH    = 3;
static constexpr int MAX_NSH= 80;     // grid = 3*80 = 240 <= 256
// Mid fallback (R19, proven 75.9us) params
static constexpr int B_N1   = 20000;
static constexpr int NB1    = 5;
static constexpr int MAX_NS1= 48;

typedef __fp16 f16x2 __attribute__((ext_vector_type(2)));

__device__ __forceinline__ unsigned lds_off(const void* p) {
    return (unsigned)(unsigned long long)p;
}

// One packed f16x2 LDS atomic add: accumulates (P,Q) in a single lane-op.
__device__ __forceinline__ void ds_pk_add(unsigned addr, float p, float q) {
    f16x2 v = __builtin_amdgcn_cvt_pkrtz(p, q);   // v_cvt_pkrtz_f16_f32
    asm volatile("ds_pk_add_f16 %0, %1" :: "v"(addr),
                 "v"(__builtin_bit_cast(unsigned, v)) : "memory");
}

// Also zeroes d_out (saves a memset dispatch; stream-ordered before reduce).
__global__ void __launch_bounds__(256) node_ef_kernel(
    const float* __restrict__ x, const float* __restrict__ xymean,
    const float* __restrict__ xystd, float2* __restrict__ ef,
    float* __restrict__ out, int n)
{
    int i = blockIdx.x * 256 + threadIdx.x;
    if (i == 0) *out = 0.0f;
    if (i >= n) return;
    float vm = fmaf(x[i * 6 + 0], xystd[0], xymean[0]);
    float va = fmaf(x[i * 6 + 1], xystd[1], xymean[1]) * DEG2RAD;
    float s, c;
    sincosf(va, &s, &c);
    ef[i] = make_float2(vm * c, vm * s);
}

// f16x2-histogram scan (R22 exact structure: 4 edges/thread/round).
__global__ void __launch_bounds__(1024) scan_h_kernel(
    const int* __restrict__ src, const int* __restrict__ dst,
    const float2* __restrict__ eattr, const float2* __restrict__ ef,
    const float* __restrict__ edgemean, const float* __restrict__ edgestd,
    unsigned* __restrict__ partial, int ne, int slice)
{
    __shared__ unsigned sAgg[B_NH];   // 156.25 KB (f16x2 per node)
    const int xp = blockIdx.x & 7, t = blockIdx.x >> 3;
    const int b  = t % NBH;
    const int sp = (t / NBH) * 8 + xp;   // same-slice blocks share an XCD/L2
    const int base = b * B_NH;
    for (int l = threadIdx.x; l < B_NH; l += 1024) sAgg[l] = 0u;
    __syncthreads();
    const int e0 = sp * slice;
    const int e1 = min(ne, e0 + slice);
    const float em0 = edgemean[0], em1 = edgemean[1];
    const float es0 = edgestd[0],  es1 = edgestd[1];

    auto process = [&](int si, int di, int e) {
        unsigned ls = (unsigned)(si - base);
        unsigned ld = (unsigned)(di - base);
        bool hs = ls < (unsigned)B_NH;
        bool hd = ld < (unsigned)B_NH;
        if (!(hs || hd)) return;
        float2 ea = eattr[e];
        float r  = fmaf(ea.x, es0, em0);
        float xr = fmaf(ea.y, es1, em1);
        float inv = MSG_SCALE / fmaf(r, r, xr * xr);
        float g  = r * inv;            // pre-scaled by 1/64
        float bb = -xr * inv;
        float2 efi = ef[si];
        float2 efj = ef[di];
        float ei_ = efi.x, fi = efi.y, ej_ = efj.x, fj = efj.y;
        // A = e_i*e_j - e_i^2 + f_i*f_j - f_i^2 ; B = f_i*e_j - e_i*f_j
        float A1 = fmaf(ei_, ej_ - ei_, fi * (fj - fi));
        float B1 = fmaf(fi, ej_, -ei_ * fj);
        if (hs) {
            ds_pk_add(lds_off(&sAgg[ls]),
                      fmaf(g, A1, bb * B1), fmaf(g, B1, -bb * A1));
        }
        if (hd) {
            float A2 = fmaf(ej_, ei_ - ej_, fj * (fi - fj));
            ds_pk_add(lds_off(&sAgg[ld]),
                      fmaf(g, A2, -bb * B1), fmaf(-g, B1, -bb * A2));
        }
    };

    // slice multiple of 4 -> int4 groups never straddle e1.
    for (int e = e0 + 4 * (int)threadIdx.x; e < e1; e += 4096) {
        int4 ss = *(const int4*)(src + e);
        int4 dd = *(const int4*)(dst + e);
        process(ss.x, dd.x, e);
        process(ss.y, dd.y, e + 1);
        process(ss.z, dd.z, e + 2);
        process(ss.w, dd.w, e + 3);
    }
    __syncthreads();
    unsigned* outp = partial + ((size_t)sp * NBH + b) * B_NH;
    for (int l = threadIdx.x; l < B_NH; l += 1024) outp[l] = sAgg[l];
}

// Reduce: 1 node/thread (grid 391 blocks -> all CUs busy), fully coalesced
// (lane i -> node i -> consecutive 4B), ns=80 independent loads = deep MLP.
__global__ void __launch_bounds__(256) reduce_h_kernel(
    const float* __restrict__ x, const float* __restrict__ y,
    const float* __restrict__ xymean, const float* __restrict__ xystd,
    const unsigned* __restrict__ partial, float* __restrict__ out,
    int n, int ns)
{
    int i = blockIdx.x * 256 + threadIdx.x;
    float v = 0.0f;
    const float inv_n = 1.0f / (float)n;
    if (i < n) {
        int b = i / B_NH;
        int l = i - b * B_NH;
        const unsigned* p = partial + (size_t)b * B_NH + l;
        const size_t stride = (size_t)NBH * B_NH;
        float P = 0.0f, Q = 0.0f;
        #pragma unroll 8
        for (int s = 0; s < ns; ++s) {
            f16x2 hv = __builtin_bit_cast(f16x2, p[(size_t)s * stride]);
            P += (float)hv.x;
            Q += (float)hv.y;
        }
        P *= MSG_UNSCALE;
        Q *= MSG_UNSCALE;
        float xd2 = fmaf(x[i * 6 + 2], xystd[2], xymean[2]);
        float xd3 = fmaf(x[i * 6 + 3], xystd[3], xymean[3]);
        float dP = xd2 - P;
        float dQ = xd3 - Q;
        float dpq = fmaf(dP, dP, dQ * dQ);
        float msep = 0.0f;
        #pragma unroll
        for (int c = 0; c < 6; ++c) {
            float dxy = x[i * 6 + c] - y[i * 6 + c];
            msep = fmaf(dxy, dxy, msep);
        }
        v = dpq * (0.01f * inv_n) + msep * (0.5f / 6.0f * inv_n);
    }
    #pragma unroll
    for (int off = 32; off; off >>= 1) v += __shfl_down(v, off, 64);
    __shared__ float ls_[4];
    int lane = threadIdx.x & 63, wv = threadIdx.x >> 6;
    if (lane == 0) ls_[wv] = v;
    __syncthreads();
    if (threadIdx.x == 0) atomicAdd(out, ls_[0] + ls_[1] + ls_[2] + ls_[3]);
}

// ---- proven f32 fallback path (R19) ----
template <int BN, bool SW>
__global__ void __launch_bounds__(1024) scan_kernel(
    const int* __restrict__ src, const int* __restrict__ dst,
    const float2* __restrict__ eattr, const float2* __restrict__ ef,
    const float* __restrict__ edgemean, const float* __restrict__ edgestd,
    float2* __restrict__ partial, int ne, int nb, int slice)
{
    __shared__ float2 sAgg[BN];
    int b, sp;
    if (SW) {
        int xp = blockIdx.x & 7, t = blockIdx.x >> 3;
        b  = t % nb;
        sp = (t / nb) * 8 + xp;
    } else {
        b  = blockIdx.x % nb;
        sp = blockIdx.x / nb;
    }
    const int base = b * BN;
    for (int l = threadIdx.x; l < BN; l += 1024) sAgg[l] = make_float2(0.f, 0.f);
    __syncthreads();
    const int e0 = sp * slice;
    const int e1 = min(ne, e0 + slice);
    const float em0 = edgemean[0], em1 = edgemean[1];
    const float es0 = edgestd[0],  es1 = edgestd[1];
    auto process = [&](int si, int di, int e) {
        unsigned ls = (unsigned)(si - base);
        unsigned ld = (unsigned)(di - base);
        bool hs = ls < (unsigned)BN;
        bool hd = ld < (unsigned)BN;
        if (!(hs || hd)) return;
        float2 ea = eattr[e];
        float r  = fmaf(ea.x, es0, em0);
        float xr = fmaf(ea.y, es1, em1);
        float inv = 1.0f / fmaf(r, r, xr * xr);
        float g  = r * inv;
        float bb = -xr * inv;
        float2 efi = ef[si];
        float2 efj = ef[di];
        float ei_ = efi.x, fi = efi.y, ej_ = efj.x, fj = efj.y;
        float A1 = fmaf(ei_, ej_ - ei_, fi * (fj - fi));
        float B1 = fmaf(fi, ej_, -ei_ * fj);
        if (hs) {
            atomicAdd(&sAgg[ls].x, fmaf(g, A1, bb * B1));
            atomicAdd(&sAgg[ls].y, fmaf(g, B1, -bb * A1));
        }
        if (hd) {
            float A2 = fmaf(ej_, ei_ - ej_, fj * (fi - fj));
            atomicAdd(&sAgg[ld].x, fmaf(g, A2, -bb * B1));
            atomicAdd(&sAgg[ld].y, fmaf(-g, B1, -bb * A2));
        }
    };
    for (int e = e0 + 4 * (int)threadIdx.x; e < e1; e += 4096) {
        int4 ss = *(const int4*)(src + e);
        int4 dd = *(const int4*)(dst + e);
        process(ss.x, dd.x, e);
        process(ss.y, dd.y, e + 1);
        process(ss.z, dd.z, e + 2);
        process(ss.w, dd.w, e + 3);
    }
    __syncthreads();
    float2* outp = partial + ((size_t)sp * nb + b) * BN;
    for (int l = threadIdx.x; l < BN; l += 1024) outp[l] = sAgg[l];
}

__global__ void __launch_bounds__(256) edge_atomic_kernel(
    const int* __restrict__ eidx, const float2* __restrict__ eattr,
    const float2* __restrict__ ef, const float* __restrict__ edgemean,
    const float* __restrict__ edgestd, float* __restrict__ agg, int ne)
{
    int e = blockIdx.x * 256 + threadIdx.x;
    if (e >= ne) return;
    int s = eidx[e];
    int d = eidx[ne + e];
    float2 ea = eattr[e];
    float r  = fmaf(ea.x, edgestd[0], edgemean[0]);
    float xr = fmaf(ea.y, edgestd[1], edgemean[1]);
    float inv = 1.0f / fmaf(r, r, xr * xr);
    float g = r * inv;
    float b = -xr * inv;
    float2 efi = ef[s];
    float2 efj = ef[d];
    float ei_ = efi.x, fi = efi.y, ej_ = efj.x, fj = efj.y;
    float A1 = fmaf(ei_, ej_ - ei_, fi * (fj - fi));
    float B1 = fmaf(fi, ej_, -ei_ * fj);
    float A2 = fmaf(ej_, ei_ - ej_, fj * (fi - fj));
    atomicAdd(&agg[2 * s],     fmaf(g, A1, b * B1));
    atomicAdd(&agg[2 * s + 1], fmaf(g, B1, -b * A1));
    atomicAdd(&agg[2 * d],     fmaf(g, A2, -b * B1));
    atomicAdd(&agg[2 * d + 1], fmaf(-g, B1, -b * A2));
}

__global__ void __launch_bounds__(256) reduce_kernel(
    const float* __restrict__ x, const float* __restrict__ y,
    const float* __restrict__ xymean, const float* __restrict__ xystd,
    const float2* __restrict__ partial, float* __restrict__ out,
    int n, int nb, int bn, int ns)
{
    int i = blockIdx.x * 256 + threadIdx.x;
    float v = 0.0f;
    if (i < n) {
        float P = 0.0f, Q = 0.0f;
        if (ns > 0) {
            int b = i / bn;
            int l = i - b * bn;
            const float2* p = partial + (size_t)b * bn + l;
            const size_t stride = (size_t)nb * bn;
            for (int s = 0; s < ns; ++s) {
                float2 a = p[(size_t)s * stride];
                P += a.x;
                Q += a.y;
            }
        } else {
            float2 a = partial[i];
            P = a.x;
            Q = a.y;
        }
        float xd2 = fmaf(x[i * 6 + 2], xystd[2], xymean[2]);
        float xd3 = fmaf(x[i * 6 + 3], xystd[3], xymean[3]);
        float dP = xd2 - P;
        float dQ = xd3 - Q;
        float dpq = fmaf(dP, dP, dQ * dQ);
        float msep = 0.0f;
        #pragma unroll
        for (int c = 0; c < 6; ++c) {
            float dxy = x[i * 6 + c] - y[i * 6 + c];
            msep = fmaf(dxy, dxy, msep);
        }
        v = dpq * (0.01f / (float)n) + msep * (0.5f / (6.0f * (float)n));
    }
    #pragma unroll
    for (int off = 32; off; off >>= 1) v += __shfl_down(v, off, 64);
    __shared__ float ls_[4];
    int lane = threadIdx.x & 63, wv = threadIdx.x >> 6;
    if (lane == 0) ls_[wv] = v;
    __syncthreads();
    if (threadIdx.x == 0) atomicAdd(out, ls_[0] + ls_[1] + ls_[2] + ls_[3]);
}

extern "C" void kernel_launch(void* const* d_in, const int* in_sizes, int n_in,
                              void* d_out, int out_size, void* d_ws, size_t ws_size,
                              hipStream_t stream) {
    const float* x        = (const float*)d_in[0];
    const int*   eidx     = (const int*)d_in[1];
    const float* eattr    = (const float*)d_in[2];
    const float* y        = (const float*)d_in[3];
    const float* xymean   = (const float*)d_in[4];
    const float* xystd    = (const float*)d_in[5];
    const float* edgemean = (const float*)d_in[6];
    const float* edgestd  = (const float*)d_in[7];
    float* out = (float*)d_out;

    const int n  = in_sizes[0] / 6;   // 100000 nodes
    const int ne = in_sizes[2] / 2;   // 1600000 edges

    const size_t ef_bytes = (size_t)n * sizeof(float2);   // 0.8 MB

    // ---- primary: f16x2 packed-atomic scan (nb=3, ns up to 80) ----
    {
        const size_t per_split = (size_t)NBH * B_NH * sizeof(unsigned); // 480 KB
        int ns = 0;
        if (ws_size > ef_bytes) {
            size_t fit = (ws_size - ef_bytes) / per_split;
            ns = (fit > (size_t)MAX_NSH) ? MAX_NSH : (int)fit;
        }
        ns &= ~7;
        if (ns >= 8) {
            unsigned* partial = (unsigned*)d_ws;
            float2* ef = (float2*)((char*)d_ws + per_split * ns);
            node_ef_kernel<<<(n + 255) / 256, 256, 0, stream>>>(
                x, xymean, xystd, ef, out, n);
            int slice = ((ne + ns - 1) / ns + 3) & ~3;   // multiple of 4
            scan_h_kernel<<<NBH * ns, 1024, 0, stream>>>(
                eidx, eidx + ne, (const float2*)eattr, ef, edgemean, edgestd,
                partial, ne, slice);
            reduce_h_kernel<<<(n + 255) / 256, 256, 0, stream>>>(
                x, y, xymean, xystd, partial, out, n, ns);
            return;
        }
    }

    (void)hipMemsetAsync(out, 0, sizeof(float), stream);

    // ---- mid: R19 f32 5-bucket scan ----
    {
        const size_t per_split = (size_t)NB1 * B_N1 * sizeof(float2); // 0.8 MB
        int ns = 0;
        if (ws_size > ef_bytes) {
            size_t fit = (ws_size - ef_bytes) / per_split;
            ns = (fit > (size_t)MAX_NS1) ? MAX_NS1 : (int)fit;
        }
        if (ns >= 1) {
            bool sw = (ns >= 8);
            if (sw) ns &= ~7;
            float2* partial = (float2*)d_ws;
            float2* ef = (float2*)((char*)d_ws + per_split * ns);
            node_ef_kernel<<<(n + 255) / 256, 256, 0, stream>>>(
                x, xymean, xystd, ef, out, n);
            int slice = ((ne + ns - 1) / ns + 3) & ~3;
            if (sw) {
                scan_kernel<B_N1, true><<<NB1 * ns, 1024, 0, stream>>>(
                    eidx, eidx + ne, (const float2*)eattr, ef, edgemean, edgestd,
                    partial, ne, NB1, slice);
            } else {
                scan_kernel<B_N1, false><<<NB1 * ns, 1024, 0, stream>>>(
                    eidx, eidx + ne, (const float2*)eattr, ef, edgemean, edgestd,
                    partial, ne, NB1, slice);
            }
            reduce_kernel<<<(n + 255) / 256, 256, 0, stream>>>(
                x, y, xymean, xystd, partial, out, n, NB1, B_N1, ns);
            return;
        }
    }

    // ---- tiny-ws fallback: global atomics ----
    {
        float2* agg = (float2*)d_ws;
        float2* ef = (float2*)((char*)d_ws + (size_t)n * sizeof(float2));
        (void)hipMemsetAsync(agg, 0, (size_t)n * sizeof(float2), stream);
        node_ef_kernel<<<(n + 255) / 256, 256, 0, stream>>>(
            x, xymean, xystd, ef, out, n);
        edge_atomic_kernel<<<(ne + 255) / 256, 256, 0, stream>>>(
            eidx, (const float2*)eattr, ef, edgemean, edgestd, (float*)agg, ne);
        reduce_kernel<<<(n + 255) / 256, 256, 0, stream>>>(
            x, y, xymean, xystd, agg, out, n, 1, 1, 0);
    }
}